// Round 9
// baseline (132.512 us; speedup 1.0000x reference)
//
#include <hip/hip_runtime.h>
#include <math.h>

typedef _Float16 half8 __attribute__((ext_vector_type(8)));
typedef _Float16 half4h __attribute__((ext_vector_type(4)));
typedef float floatx4 __attribute__((ext_vector_type(4)));

#define HDIM 256
#define NC 15        // value + 4 grad + 10 hess
#define NCP 16       // comps padded to 16 (comp 15 = always zero)
#define SPB 8        // samples per block
#define MR 128       // M rows = NCP * SPB
#define NWAVE 4
#define NT 4         // n-tiles per wave (64 neurons)

// Row mapping: m = 16*(c>>1) + 4*(sl>>1) + 2*(sl&1) + (c&1).
// => MFMA C/D lane (col,q) rows m=16mt+4q+r hold comp c=2mt+(r&1) of sample
//    sl=2q+(r>>1): every lane owns ALL 16 comps of 2 samples -> chain rule
//    register-local, no hold-across-GEMM (the R3-R7 spill lesson).
// LDS: st[128][256] f16 = 65536 B; chunk-of-8-f16 XOR swizzle
//    phys_chunk = logical_chunk ^ (m & 31).

// ---------------------------------------------------------------------------
// Per-sample analytic Einstein tensor. ARRAY-FREE: dgv/ddg/Hf/Gm are
// constant-folded lambdas over ~20 scalars (R8 lesson: materializing
// ddg[64]+Gm[64] forced ~180 live floats -> global spill pressure).
// ---------------------------------------------------------------------------
__device__ __forceinline__ void einstein_tail(
    float f, const float* Gf, const float* Hs, float r, float th,
    float* __restrict__ outp)
{
    const float sn = sinf(th), cs = cosf(th);
    const float E  = expf(f);
    const float r2 = r * r;

    float gi[4];
    gi[0] = -1.f; gi[1] = 1.f / E; gi[2] = 1.f / r2; gi[3] = 1.f / (r2 * sn * sn);

    auto Hfun = [&](int k, int l) -> float {        // symmetric Hessian lookup
        int a = k < l ? k : l, b2 = k < l ? l : k;
        int idx = (a == 0) ? b2 : (a == 1) ? 3 + b2 : (a == 2) ? 5 + b2 : 9;
        return Hs[idx];
    };
    auto dgv = [&](int a, int k) -> float {         // d_k g_aa
        if (a == 1) return E * Gf[k];
        if (a == 2) return (k == 1) ? 2.f * r : 0.f;
        if (a == 3) {
            if (k == 1) return 2.f * r * sn * sn;
            if (k == 2) return 2.f * r2 * sn * cs;
        }
        return 0.f;
    };
    auto ddg = [&](int a, int k, int l) -> float {  // d_k d_l g_aa
        if (a == 1) return E * fmaf(Gf[k], Gf[l], Hfun(k, l));
        if (a == 2) return (k == 1 && l == 1) ? 2.f : 0.f;
        if (a == 3) {
            if (k == 1 && l == 1) return 2.f * sn * sn;
            if ((k == 1 && l == 2) || (k == 2 && l == 1)) return 4.f * r * sn * cs;
            if (k == 2 && l == 2) return 2.f * r2 * (cs * cs - sn * sn);
        }
        return 0.f;
    };
    auto SYMF = [&](int a, int i, int jx) -> float {
        float sy = 0.f;
        if (a == i)  sy += dgv(a, jx);
        if (a == jx) sy += dgv(a, i);
        if (i == jx) sy -= dgv(i, a);
        return sy;
    };
    auto DF = [&](int a, int i, int jx, int k) -> float {
        float ds = 0.f;
        if (a == i)  ds += ddg(a, jx, k);
        if (a == jx) ds += ddg(a, i, k);
        if (i == jx) ds -= ddg(i, a, k);
        return 0.5f * (gi[a] * ds - gi[a] * gi[a] * dgv(a, k) * SYMF(a, i, jx));
    };
    auto Gm = [&](int a, int i, int jx) -> float {
        return 0.5f * gi[a] * SYMF(a, i, jx);
    };

    float ric[4][4];
#pragma unroll
    for (int b = 0; b < 4; ++b)
#pragma unroll
        for (int d = 0; d < 4; ++d) {
            float sum = 0.f;
#pragma unroll
            for (int a = 0; a < 4; ++a) {
                sum += DF(a, d, b, a) - DF(a, a, b, d);
#pragma unroll
                for (int e = 0; e < 4; ++e)
                    sum += Gm(a, a, e) * Gm(e, d, b) - Gm(a, d, e) * Gm(e, a, b);
            }
            ric[b][d] = sum;
        }

    float Rs = 0.f;
#pragma unroll
    for (int b = 0; b < 4; ++b) Rs += gi[b] * ric[b][b];

#pragma unroll
    for (int a = 0; a < 4; ++a)
#pragma unroll
        for (int b = 0; b < 4; ++b) {
            float v = gi[a] * gi[b] * ric[a][b];
            if (a == b) v -= 0.5f * gi[a] * Rs;
            outp[a * 4 + b] = v;
        }
}

// ---------------------------------------------------------------------------
// Coalesced 64x64 LDS-tile transpose: Wt[m][j*256+k] = (f16)W_m[k*256+j].
// 1024 threads/block -> 4 iters/phase.
// ---------------------------------------------------------------------------
__global__ __launch_bounds__(1024) void pack_wt(
    const float* __restrict__ W2, const float* __restrict__ W3,
    _Float16* __restrict__ Wt)
{
    __shared__ float t[64][65];
    const int m    = blockIdx.x >> 4;
    const float* W = m ? W3 : W2;
    const int tile = blockIdx.x & 15;
    const int k0 = (tile >> 2) * 64, j0 = (tile & 3) * 64;
    const int tx = threadIdx.x & 63, ty = threadIdx.x >> 6;   // 64 x 16
#pragma unroll
    for (int i = 0; i < 4; ++i) {
        int k = ty + i * 16;
        t[k][tx] = W[(k0 + k) * HDIM + j0 + tx];              // coalesced read
    }
    __syncthreads();
#pragma unroll
    for (int i = 0; i < 4; ++i) {
        int jj = ty + i * 16;
        Wt[(size_t)m * HDIM * HDIM + (j0 + jj) * HDIM + k0 + tx] =
            (_Float16)t[tx][jj];                              // coalesced write
    }
}

// ---------------------------------------------------------------------------
// Fused kernel. Block = 256 thr (4 waves), 8 samples, __launch_bounds__(256,2)
// -> 256 regs/wave, 2 blocks/CU. acc[8][4] = 128 AGPR; all phases keep arch
// VGPR use < 128 (produce1 runs in two 4-col passes; einstein_tail is
// array-free) -> no scratch spill.
// ---------------------------------------------------------------------------
template <bool TW>
__global__ __launch_bounds__(256, 2) void mlp_fused(
    const float* __restrict__ coords,
    const float* __restrict__ W1, const float* __restrict__ b1,
    const float* __restrict__ W2, const float* __restrict__ b2,
    const float* __restrict__ W3, const float* __restrict__ b3,
    const float* __restrict__ Wo, const float* __restrict__ bo,
    const _Float16* __restrict__ Wt,   // packed f16 W2^T | W3^T (TW only)
    float* __restrict__ out, int B)
{
    __shared__ __align__(16) _Float16 st[MR * HDIM];   // 65,536 B exactly

    const int tid  = threadIdx.x;
    const int w    = tid >> 6;       // wave 0..3
    const int lane = tid & 63;
    const int col  = lane & 15;
    const int q    = lane >> 4;
    const int s0   = blockIdx.x * SPB;

    floatx4 acc[8][NT];              // 128 unified regs (AGPR)

    auto f4get = [](const float4& v, int i) -> float {
        switch (i & 3) { case 0: return v.x; case 1: return v.y;
                         case 2: return v.z; default: return v.w; }
    };

    // ---- layer-1 producer: thread = (sample sl, 8-col chunk tc), 2 passes --
    auto produce1 = [&]() {
        const int sl = tid & 7;
        const int tc = tid >> 3;               // 0..31
        int ss = s0 + sl; if (ss >= B) ss = B - 1;
        const float x0 = coords[ss * 4 + 0];
        const float x1 = coords[ss * 4 + 1];
        const float x2 = coords[ss * 4 + 2];
        const float x3 = coords[ss * 4 + 3];
        const int jg = tc * 8;
#pragma unroll
        for (int h = 0; h < 2; ++h) {          // 4 columns per pass
            float4 wa0 = *(const float4*)&W1[0 * HDIM + jg + 4 * h];
            float4 wa1 = *(const float4*)&W1[1 * HDIM + jg + 4 * h];
            float4 wa2 = *(const float4*)&W1[2 * HDIM + jg + 4 * h];
            float4 wa3 = *(const float4*)&W1[3 * HDIM + jg + 4 * h];
            float4 bb  = *(const float4*)&b1[jg + 4 * h];
            half4h ch4[NCP];                   // 32 VGPRs
#pragma unroll
            for (int jj = 0; jj < 4; ++jj) ch4[15][jj] = (_Float16)0.f;
#pragma unroll
            for (int jj = 0; jj < 4; ++jj) {
                float w0 = f4get(wa0, jj), w1 = f4get(wa1, jj);
                float w2v = f4get(wa2, jj), w3v = f4get(wa3, jj);
                float a = f4get(bb, jj);
                a = fmaf(x0, w0, a); a = fmaf(x1, w1, a);
                a = fmaf(x2, w2v, a); a = fmaf(x3, w3v, a);
                float v = tanhf(a), tp = 1.f - v * v, m2 = -2.f * v * tp;
                float g[4] = {w0, w1, w2v, w3v};
                ch4[0][jj] = (_Float16)v;
#pragma unroll
                for (int k = 0; k < 4; ++k) ch4[1 + k][jj] = (_Float16)(tp * g[k]);
                int idx = 5;
#pragma unroll
                for (int aa = 0; aa < 4; ++aa)
#pragma unroll
                    for (int bb2 = aa; bb2 < 4; ++bb2) {
                        ch4[idx][jj] = (_Float16)(m2 * g[aa] * g[bb2]); ++idx;
                    }
            }
#pragma unroll
            for (int c = 0; c < NCP; ++c) {
                const int m = 16 * (c >> 1) + 4 * (sl >> 1) + 2 * (sl & 1) + (c & 1);
                const int addr = m * HDIM + (((tc ^ m) & 31) << 3) + 4 * h;
                *(half4h*)&st[addr] = ch4[c];
            }
        }
    };

    auto init_acc = [&](const float* __restrict__ b) {
#pragma unroll
        for (int nt = 0; nt < NT; ++nt) {
            float bj = b[w * 64 + nt * 16 + col];
#pragma unroll
            for (int mt = 0; mt < 8; ++mt)
#pragma unroll
                for (int r = 0; r < 4; ++r) acc[mt][nt][r] = 0.f;
            acc[0][nt][0] = bj;    // comp 0, sample-local 0
            acc[0][nt][2] = bj;    // comp 0, sample-local 1
        }
    };

    // full-K GEMM: A = st (swizzled LDS), B = Wt rows (f16, k-contiguous)
    auto gemm_full = [&](const float* __restrict__ W, int layer) {
#pragma unroll
        for (int ks = 0; ks < 8; ++ks) {
            const int kg = ks * 32 + q * 8;
            half8 bf[NT];
#pragma unroll
            for (int nt = 0; nt < NT; ++nt) {
                const int j = w * 64 + nt * 16 + col;
                if constexpr (TW) {
                    bf[nt] = *(const half8*)&Wt[((size_t)layer * HDIM + j) * HDIM + kg];
                } else {
#pragma unroll
                    for (int i = 0; i < 8; ++i)
                        bf[nt][i] = (_Float16)W[(kg + i) * HDIM + j];
                }
            }
            const int lc = ks * 4 + q;         // logical chunk
#pragma unroll
            for (int mt = 0; mt < 8; ++mt) {
                const int m = 16 * mt + col;
                half8 af = *(const half8*)&st[m * HDIM + (((lc ^ m) & 31) << 3)];
#pragma unroll
                for (int nt = 0; nt < NT; ++nt)
                    acc[mt][nt] = __builtin_amdgcn_mfma_f32_16x16x32_f16(
                        af, bf[nt], acc[mt][nt], 0, 0, 0);
            }
        }
    };

    // tanh chain rule + immediate LDS store (register-local, no hold)
    auto transform_store = [&]() {
#pragma unroll
        for (int nt = 0; nt < NT; ++nt) {
            const int j = w * 64 + nt * 16 + col;
            const int jc = j >> 3, jb = j & 7;
#pragma unroll
            for (int sv = 0; sv < 2; ++sv) {           // sample-local
                float pre[NCP];
#pragma unroll
                for (int c = 0; c < NCP; ++c)
                    pre[c] = acc[c >> 1][nt][sv * 2 + (c & 1)];
                float v = tanhf(pre[0]), tp = 1.f - v * v, m2 = -2.f * v * tp;
                float g[4] = {pre[1], pre[2], pre[3], pre[4]};
                float ns[NCP];
                ns[0] = v;
#pragma unroll
                for (int k = 0; k < 4; ++k) ns[1 + k] = tp * g[k];
                int idx = 5;
#pragma unroll
                for (int aa = 0; aa < 4; ++aa)
#pragma unroll
                    for (int bb2 = aa; bb2 < 4; ++bb2) {
                        ns[idx] = fmaf(tp, pre[idx], m2 * g[aa] * g[bb2]); ++idx;
                    }
                ns[15] = 0.f;
#pragma unroll
                for (int c = 0; c < NCP; ++c) {
                    const int m = 16 * (c >> 1) + 4 * q + 2 * sv + (c & 1);
                    st[m * HDIM + (((jc ^ m) & 31) << 3) + jb] = (_Float16)ns[c];
                }
            }
        }
    };

    // ================= pipeline =================
    produce1();
    __syncthreads();
    init_acc(b2);
    gemm_full(W2, 0);
    __syncthreads();                  // layer-1 state consumed
    transform_store();                // layer-2 state -> st (immediate)
    __syncthreads();
    init_acc(b3);
    gemm_full(W3, 1);

    // ---- epilogue: layer-3 tanh chain + Wo dot ----
    __syncthreads();                  // st consumed; alias for partials
    float* part = (float*)st;         // [0, 480): part[w][sl][c]
    float* fin  = ((float*)st) + 512; // [512, 640): fin[sl][16]
    float wo[NT];
#pragma unroll
    for (int nt = 0; nt < NT; ++nt) wo[nt] = Wo[w * 64 + nt * 16 + col];

    float on2[2][NC];
#pragma unroll
    for (int sv = 0; sv < 2; ++sv)
#pragma unroll
        for (int c = 0; c < NC; ++c) on2[sv][c] = 0.f;
#pragma unroll
    for (int nt = 0; nt < NT; ++nt)
#pragma unroll
        for (int sv = 0; sv < 2; ++sv) {
            float pre[NCP];
#pragma unroll
            for (int c = 0; c < NCP; ++c)
                pre[c] = acc[c >> 1][nt][sv * 2 + (c & 1)];
            float v = tanhf(pre[0]), tp = 1.f - v * v, m2 = -2.f * v * tp;
            float g[4] = {pre[1], pre[2], pre[3], pre[4]};
            on2[sv][0] = fmaf(wo[nt], v, on2[sv][0]);
#pragma unroll
            for (int k = 0; k < 4; ++k)
                on2[sv][1 + k] = fmaf(wo[nt], tp * g[k], on2[sv][1 + k]);
            int idx = 5;
#pragma unroll
            for (int aa = 0; aa < 4; ++aa)
#pragma unroll
                for (int bb2 = aa; bb2 < 4; ++bb2) {
                    on2[sv][idx] = fmaf(wo[nt],
                        fmaf(tp, pre[idx], m2 * g[aa] * g[bb2]), on2[sv][idx]);
                    ++idx;
                }
        }
#pragma unroll
    for (int mask = 1; mask < 16; mask <<= 1)
#pragma unroll
        for (int sv = 0; sv < 2; ++sv)
#pragma unroll
            for (int c = 0; c < NC; ++c)
                on2[sv][c] += __shfl_xor(on2[sv][c], mask, 64);
    if (col == 0) {
#pragma unroll
        for (int sv = 0; sv < 2; ++sv)
#pragma unroll
            for (int c = 0; c < NC; ++c)
                part[(w * SPB + 2 * q + sv) * NC + c] = on2[sv][c];
    }
    __syncthreads();
    if (tid < SPB * NC) {             // 120 threads
        const int sl = tid / NC, c = tid % NC;
        float v = 0.f;
#pragma unroll
        for (int ww = 0; ww < NWAVE; ++ww) v += part[(ww * SPB + sl) * NC + c];
        if (c == 0) v += bo[0];
        fin[sl * 16 + c] = v;
    }
    __syncthreads();
    if (tid < SPB) {
        int s = s0 + tid;
        if (s < B) {
            float f = fin[tid * 16 + 0];
            float Gf[4], Hs[10];
#pragma unroll
            for (int k = 0; k < 4; ++k) Gf[k] = fin[tid * 16 + 1 + k];
#pragma unroll
            for (int qq = 0; qq < 10; ++qq) Hs[qq] = fin[tid * 16 + 5 + qq];
            float r  = coords[s * 4 + 1];
            float th = coords[s * 4 + 2];
            float res[16];
            einstein_tail(f, Gf, Hs, r, th, res);
#pragma unroll
            for (int e = 0; e < 16; ++e) out[s * 16 + e] = res[e];
        }
    }
}

extern "C" void kernel_launch(void* const* d_in, const int* in_sizes, int n_in,
                              void* d_out, int out_size, void* d_ws, size_t ws_size,
                              hipStream_t stream) {
    const float* coords = (const float*)d_in[0];
    const float* W1 = (const float*)d_in[1];
    const float* b1 = (const float*)d_in[2];
    const float* W2 = (const float*)d_in[3];
    const float* b2 = (const float*)d_in[4];
    const float* W3 = (const float*)d_in[5];
    const float* b3 = (const float*)d_in[6];
    const float* Wo = (const float*)d_in[7];
    const float* bo = (const float*)d_in[8];
    float* out = (float*)d_out;
    const int B = in_sizes[0] / 4;
    const int nblocks = (B + SPB - 1) / SPB;

    const size_t wt_bytes = (size_t)2 * HDIM * HDIM * sizeof(_Float16);
    if (ws_size >= wt_bytes) {
        _Float16* Wt = (_Float16*)d_ws;
        pack_wt<<<32, 1024, 0, stream>>>(W2, W3, Wt);
        mlp_fused<true><<<nblocks, 256, 0, stream>>>(
            coords, W1, b1, W2, b2, W3, b3, Wo, bo, Wt, out, B);
    } else {
        mlp_fused<false><<<nblocks, 256, 0, stream>>>(
            coords, W1, b1, W2, b2, W3, b3, Wo, bo, nullptr, out, B);
    }
}